// Round 10
// baseline (453.458 us; speedup 1.0000x reference)
//
#include <hip/hip_runtime.h>

// Problem constants (B=2, S=4096, D=512, H=8, Dh=64). f32 I/O, bf16 MFMA inside.
#define MTOT 8192  // B*S

typedef __attribute__((ext_vector_type(8))) short bf16x8;
typedef __attribute__((ext_vector_type(4))) float f32x4;

#if __has_builtin(__builtin_amdgcn_exp2f)
#define EXP2F __builtin_amdgcn_exp2f
#else
#define EXP2F exp2f
#endif

#define SC 0.18033688011112042f  // (1/8) * log2(e), folded into K
#define LDP 72                   // bf16 LDS row stride: 36 dw == 4 mod 32
#define CTS 136                  // gemm epilogue C-tile stride (el)
#define MOS 68                   // f32 merge-buffer stride: 68 == 4 mod 32

static __device__ __forceinline__ unsigned short tb(float f) {
  union { float f; unsigned int i; } x;
  x.f = f;
  return (unsigned short)(x.i >> 16);
}
static __device__ __forceinline__ unsigned int pkt(float a, float b) {
  union { float f; unsigned int i; } xa, xb;
  xa.f = a; xb.f = b;
  return (xa.i >> 16) | (xb.i & 0xFFFF0000u);
}
static __device__ __forceinline__ bf16x8 ld8f32_bf16(const float* __restrict__ p) {
  f32x4 lo = *(const f32x4*)p;
  f32x4 hi = *(const f32x4*)(p + 4);
  union { unsigned int u[4]; bf16x8 v; } r;
  r.u[0] = pkt(lo[0], lo[1]);
  r.u[1] = pkt(lo[2], lo[3]);
  r.u[2] = pkt(hi[0], hi[1]);
  r.u[3] = pkt(hi[2], hi[3]);
  return r.v;
}
static __device__ __forceinline__ bf16x8 comb64(uint2 lo, uint2 hi) {
  union { uint2 p[2]; bf16x8 v; } r;
  r.p[0] = lo; r.p[1] = hi;
  return r.v;
}

// ---------------------------------------------------------------------------
// Kernel 1: projection GEMM (R8 structure; R9's register-prefetch reverted).
// Columns: [0,512) Q -> Q_ws[bh][s][dh]; [512,1024) V -> Vt_ws[bh][dh][s];
//          [1024,1536) K (*SC) -> K_ws[bh][s][dh] (only when nct==12).
// ---------------------------------------------------------------------------
__global__ __launch_bounds__(256) void gemm_qvk(
    const float* __restrict__ mf,
    const float* __restrict__ Wc,
    const float* __restrict__ bc,
    const float* __restrict__ Wv,
    const float* __restrict__ bv,
    unsigned short* __restrict__ ws,
    int nct)
{
  const int bid = blockIdx.x;
  const int tn = bid % nct, tm = bid / nct;
  const int w = threadIdx.x >> 6, lane = threadIdx.x & 63;
  const int n = lane & 15, q = lane >> 4;

  __shared__ alignas(16) unsigned short smem[2 * 128 * LDP];  // As | Bs; Ct overlay
  unsigned short* As = smem;
  unsigned short* Bs = smem + 128 * LDP;

  f32x4 acc[4][4] = {};
  const int rowA0 = tm * 128, colB0 = tn * 128;
  const int sr = threadIdx.x >> 4;           // staging row 0..15
  const int sc4 = (threadIdx.x & 15) * 4;    // f32 col offset (16B)

  for (int kc = 0; kc < 512; kc += 64) {
    __syncthreads();
#pragma unroll
    for (int rr = 0; rr < 8; ++rr) {
      const int row = rr * 16 + sr;
      f32x4 av = *(const f32x4*)(mf + (size_t)(rowA0 + row) * 512 + kc + sc4);
      uint2 ap; ap.x = pkt(av[0], av[1]); ap.y = pkt(av[2], av[3]);
      *(uint2*)(&As[row * LDP + sc4]) = ap;
      const int cB = colB0 + row;
      const float* bsrc = (cB < 1024) ? (Wc + (size_t)cB * 512)
                                      : (Wv + (size_t)(cB - 1024) * 512);
      f32x4 bvx = *(const f32x4*)(bsrc + kc + sc4);
      uint2 bp; bp.x = pkt(bvx[0], bvx[1]); bp.y = pkt(bvx[2], bvx[3]);
      *(uint2*)(&Bs[row * LDP + sc4]) = bp;
    }
    __syncthreads();
#pragma unroll
    for (int ks = 0; ks < 2; ++ks) {
      bf16x8 a[4], b[4];
#pragma unroll
      for (int si = 0; si < 4; ++si)
        a[si] = *(const bf16x8*)(&As[((w >> 1) * 64 + si * 16 + n) * LDP + ks * 32 + q * 8]);
#pragma unroll
      for (int sj = 0; sj < 4; ++sj)
        b[sj] = *(const bf16x8*)(&Bs[((w & 1) * 64 + sj * 16 + n) * LDP + ks * 32 + q * 8]);
#pragma unroll
      for (int si = 0; si < 4; ++si)
#pragma unroll
        for (int sj = 0; sj < 4; ++sj)
          acc[si][sj] = __builtin_amdgcn_mfma_f32_16x16x32_bf16(a[si], b[sj], acc[si][sj], 0, 0, 0);
    }
  }

  // ---- epilogue: LDS transpose (Ct overlays As/Bs) then coalesced stores ----
  __syncthreads();
  unsigned short* Ct = smem;  // [128][CTS]
  const bool isV = (tn >= 4 && tn < 8);
  const int rl0 = (w >> 1) * 64, cl0 = (w & 1) * 64;

  if (!isV) {
    const bool isK = (tn >= 8);
#pragma unroll
    for (int sj = 0; sj < 4; ++sj) {
      const int c = colB0 + sj * 16 + n;
      const float bias = isK ? bv[c - 1024] : bc[c];
#pragma unroll
      for (int si = 0; si < 4; ++si)
#pragma unroll
        for (int r = 0; r < 4; ++r) {
          float v = acc[si][sj][r] + bias;
          if (isK) v *= SC;
          Ct[(rl0 + si * 16 + q * 4 + r) * CTS + cl0 + sj * 16 + n] = tb(v);
        }
    }
  } else {
#pragma unroll
    for (int sj = 0; sj < 4; ++sj) {
      const float bias = bc[colB0 + sj * 16 + n];
#pragma unroll
      for (int si = 0; si < 4; ++si) {
        uint2 pk;
        pk.x = pkt(acc[si][sj][0] + bias, acc[si][sj][1] + bias);
        pk.y = pkt(acc[si][sj][2] + bias, acc[si][sj][3] + bias);
        *(uint2*)(&Ct[(cl0 + sj * 16 + n) * CTS + rl0 + si * 16 + q * 4]) = pk;
      }
    }
  }
  __syncthreads();

  const int rk = threadIdx.x & 7, rr2 = threadIdx.x >> 3;
#pragma unroll
  for (int rp = 0; rp < 4; ++rp) {
    const int row = rp * 32 + rr2;
#pragma unroll
    for (int ch = 0; ch < 2; ++ch) {
      const int col = ch * 64 + rk * 8;
      bf16x8 v = *(const bf16x8*)(&Ct[row * CTS + col]);
      if (!isV) {
        const int srow = rowA0 + row;
        const int bb = srow >> 12, ss = srow & 4095;
        const int cg = colB0 + col;
        const int cl = (cg >= 1024) ? (cg - 1024) : cg;
        const int hh = cl >> 6, dh0 = cl & 63;
        unsigned short* base = (cg >= 1024) ? (ws + (size_t)2 * MTOT * 512) : ws;
        *(bf16x8*)(base + ((size_t)((bb * 8 + hh) * 4096 + ss)) * 64 + dh0) = v;
      } else {
        const int cv = (tn - 4) * 128 + row;
        const int hh = cv >> 6, dh0 = cv & 63;
        const int sg = rowA0 + col;
        const int bb = sg >> 12, ss = sg & 4095;
        *(bf16x8*)(ws + (size_t)MTOT * 512 +
                   ((size_t)((bb * 8 + hh) * 64 + dh0)) * 4096 + ss) = v;
      }
    }
  }
}

// ---------------------------------------------------------------------------
// Kernel 2: flash attention, phase-wise register-P, 4-wave blocks.
//  - block = 256 thr = 4 waves: (wi = i-half of 32 rows, wj = j-half of 2048)
//  - j-loop phases: [all QK] -> [reload bq] -> [all exp2/pack] -> [all PV]
//    -> [reload bvv]; single-buffered streams (regs dead at reload points)
//  - P never leaves registers (QK transposed-C == PV A-frag under pi_s)
//  - launch_bounds(256,3): cap regs ~170 -> 3 waves/SIMD (R8/R9 were at 2)
// ---------------------------------------------------------------------------
template <bool KWS>
__global__ __launch_bounds__(256, 3) void attn_kernel(
    const unsigned short* __restrict__ qvws,
    const float* __restrict__ mf,
    const float* __restrict__ Wv,
    const float* __restrict__ bv,
    float* __restrict__ out)
{
  const int bid = blockIdx.x;
  const int bh = ((bid & 7) << 1) | ((bid >> 3) & 1);  // XCD-local bh pairing
  const int ib = bid >> 4;
  const int b_ = bh >> 3, h = bh & 7;
  const int w = threadIdx.x >> 6, lane = threadIdx.x & 63;
  const int wi = w >> 1, wj = w & 1;
  const int n = lane & 15, q = lane >> 4;
  const int i0 = ib * 64;              // block's 64 i-rows
  const int iw = i0 + wi * 32;         // wave's 32 i-rows

  __shared__ alignas(16) float mO[64 * MOS];  // merge/out staging (17.4 KB)
  __shared__ float lbuf[64];

  const unsigned short* Qb = qvws + (size_t)(bh * 4096) * 64;
  const unsigned short* Vb = qvws + (size_t)MTOT * 512 + (size_t)(bh * 64) * 4096;

  bf16x8 aK[2][2];
  if (KWS) {
    const unsigned short* Kb = qvws + (size_t)2 * MTOT * 512 + (size_t)(bh * 4096) * 64;
#pragma unroll
    for (int sub = 0; sub < 2; ++sub)
#pragma unroll
      for (int s = 0; s < 2; ++s)
        aK[sub][s] = *(const bf16x8*)(Kb + (size_t)(iw + sub * 16 + n) * 64 + s * 32 + q * 8);
  } else {
    // Fallback: 4 waves each compute 16 K rows (i0 + w*16) via LDS overlay.
    unsigned short* Ks = (unsigned short*)mO;
    f32x4 ka[4] = {};
    for (int kk = 0; kk < 512; kk += 32) {
      bf16x8 a = ld8f32_bf16(mf + (size_t)(b_ * 4096 + i0 + w * 16 + n) * 512 + kk + q * 8);
#pragma unroll
      for (int t = 0; t < 4; ++t) {
        bf16x8 bw = ld8f32_bf16(Wv + (size_t)(h * 64 + t * 16 + n) * 512 + kk + q * 8);
        ka[t] = __builtin_amdgcn_mfma_f32_16x16x32_bf16(a, bw, ka[t], 0, 0, 0);
      }
    }
#pragma unroll
    for (int t = 0; t < 4; ++t) {
      const float bias = bv[h * 64 + t * 16 + n];
#pragma unroll
      for (int r = 0; r < 4; ++r)
        Ks[(w * 16 + q * 4 + r) * LDP + t * 16 + n] = tb((ka[t][r] + bias) * SC);
    }
    __syncthreads();
#pragma unroll
    for (int sub = 0; sub < 2; ++sub)
#pragma unroll
      for (int s = 0; s < 2; ++s)
        aK[sub][s] = *(const bf16x8*)(&Ks[(wi * 32 + sub * 16 + n) * LDP + s * 32 + q * 8]);
    __syncthreads();
  }

  f32x4 o[2][4] = {};
  f32x4 lacc[2] = {};
  const bf16x8 ones = {(short)0x3F80, (short)0x3F80, (short)0x3F80, (short)0x3F80,
                       (short)0x3F80, (short)0x3F80, (short)0x3F80, (short)0x3F80};
  const int jbase = wj * 2048;

  // Single-buffered streaming frags.
  bf16x8 bq[4][2], bvv[4][2];
#pragma unroll
  for (int jt = 0; jt < 4; ++jt)
#pragma unroll
    for (int s = 0; s < 2; ++s)
      bq[jt][s] = *(const bf16x8*)(Qb + (size_t)(jbase + jt * 16 + n) * 64 + s * 32 + q * 8);
#pragma unroll
  for (int t = 0; t < 4; ++t)
#pragma unroll
    for (int s = 0; s < 2; ++s) {
      const unsigned short* p0 = Vb + (size_t)(t * 16 + n) * 4096 + jbase + 32 * s + 4 * q;
      bvv[t][s] = comb64(*(const uint2*)p0, *(const uint2*)(p0 + 16));
    }

  for (int it = 0; it < 32; ++it) {
    const int jn = jbase + ((it + 1) & 31) * 64;  // next j-tile (wraps)

    // ---- Phase 1: ALL QK (16 MFMAs, 8 independent depth-2 chains) ----
    f32x4 c[2][4] = {};
#pragma unroll
    for (int sub = 0; sub < 2; ++sub)
#pragma unroll
      for (int jt = 0; jt < 4; ++jt)
#pragma unroll
        for (int s = 0; s < 2; ++s)
          c[sub][jt] = __builtin_amdgcn_mfma_f32_16x16x32_bf16(bq[jt][s], aK[sub][s], c[sub][jt], 0, 0, 0);

    // ---- Phase 2: bq regs dead -> issue next-iter Q loads now ----
#pragma unroll
    for (int jt = 0; jt < 4; ++jt)
#pragma unroll
      for (int s = 0; s < 2; ++s)
        bq[jt][s] = *(const bf16x8*)(Qb + (size_t)(jn + jt * 16 + n) * 64 + s * 32 + q * 8);

    // ---- Phase 3: ALL exp2 + pack into PV A-frags (no LDS) ----
    bf16x8 pa[2][2];
#pragma unroll
    for (int sub = 0; sub < 2; ++sub)
#pragma unroll
      for (int s = 0; s < 2; ++s) {
        union { unsigned int u[4]; bf16x8 v; } p;
        p.u[0] = pkt(EXP2F(c[sub][2 * s][0]), EXP2F(c[sub][2 * s][1]));
        p.u[1] = pkt(EXP2F(c[sub][2 * s][2]), EXP2F(c[sub][2 * s][3]));
        p.u[2] = pkt(EXP2F(c[sub][2 * s + 1][0]), EXP2F(c[sub][2 * s + 1][1]));
        p.u[3] = pkt(EXP2F(c[sub][2 * s + 1][2]), EXP2F(c[sub][2 * s + 1][3]));
        pa[sub][s] = p.v;
      }

    // ---- Phase 4: ALL PV + l (20 MFMAs, width 10) ----
#pragma unroll
    for (int sub = 0; sub < 2; ++sub)
#pragma unroll
      for (int s = 0; s < 2; ++s) {
        lacc[sub] = __builtin_amdgcn_mfma_f32_16x16x32_bf16(pa[sub][s], ones, lacc[sub], 0, 0, 0);
#pragma unroll
        for (int t = 0; t < 4; ++t)
          o[sub][t] = __builtin_amdgcn_mfma_f32_16x16x32_bf16(pa[sub][s], bvv[t][s], o[sub][t], 0, 0, 0);
      }

    // ---- Phase 5: bvv regs dead -> issue next-iter V loads ----
#pragma unroll
    for (int t = 0; t < 4; ++t)
#pragma unroll
      for (int s = 0; s < 2; ++s) {
        const unsigned short* p0 = Vb + (size_t)(t * 16 + n) * 4096 + jn + 32 * s + 4 * q;
        bvv[t][s] = comb64(*(const uint2*)p0, *(const uint2*)(p0 + 16));
      }
  }

  // ---- merge j-halves (exact f32) + coalesced epilogue ----
  __syncthreads();
  if (wj == 1) {
#pragma unroll
    for (int sub = 0; sub < 2; ++sub) {
#pragma unroll
      for (int t = 0; t < 4; ++t)
#pragma unroll
        for (int r = 0; r < 4; ++r)
          mO[(wi * 32 + sub * 16 + q * 4 + r) * MOS + t * 16 + n] = o[sub][t][r];
      if (n == 0)
#pragma unroll
        for (int r = 0; r < 4; ++r)
          lbuf[wi * 32 + sub * 16 + q * 4 + r] = lacc[sub][r];
    }
  }
  __syncthreads();
  if (wj == 0) {
#pragma unroll
    for (int sub = 0; sub < 2; ++sub) {
      float li[4];
#pragma unroll
      for (int r = 0; r < 4; ++r)
        li[r] = 1.0f / (lacc[sub][r] + lbuf[wi * 32 + sub * 16 + q * 4 + r]);
#pragma unroll
      for (int t = 0; t < 4; ++t)
#pragma unroll
        for (int r = 0; r < 4; ++r) {
          const int mrow = wi * 32 + sub * 16 + q * 4 + r;
          const int mcol = t * 16 + n;
          mO[mrow * MOS + mcol] = (o[sub][t][r] + mO[mrow * MOS + mcol]) * li[r];
        }
    }
  }
  __syncthreads();
  // Coalesced f32x4 stores: 4 threads per row cover 64 f32 (256B).
  const int orow = threadIdx.x >> 2, oc = (threadIdx.x & 3) * 16;
  const size_t obase = (size_t)(b_ * 4096 + i0 + orow) * 512 + h * 64 + oc;
#pragma unroll
  for (int c4 = 0; c4 < 4; ++c4) {
    f32x4 v = *(const f32x4*)(&mO[orow * MOS + oc + c4 * 4]);
    f32x4 m = *(const f32x4*)(mf + obase + c4 * 4);
    *(f32x4*)(out + obase + c4 * 4) = v + m;
  }
}

extern "C" void kernel_launch(void* const* d_in, const int* in_sizes, int n_in,
                              void* d_out, int out_size, void* d_ws, size_t ws_size,
                              hipStream_t stream) {
  const float* mf = (const float*)d_in[0];  // (2,4096,512) f32
  const float* Wc = (const float*)d_in[1];  // (1024,512) f32
  const float* bc = (const float*)d_in[2];  // (1024,) f32
  const float* Wv = (const float*)d_in[3];  // (512,512) f32
  const float* bv = (const float*)d_in[4];  // (512,) f32
  float* out = (float*)d_out;
  unsigned short* ws = (unsigned short*)d_ws;

  const bool kws = ws_size >= (size_t)3 * MTOT * 512 * 2;  // Q+V^T+K bf16 = 24 MiB
  const int nct = kws ? 12 : 8;

  gemm_qvk<<<64 * nct, 256, 0, stream>>>(mf, Wc, bc, Wv, bv, ws, nct);
  if (kws)
    attn_kernel<true><<<1024, 256, 0, stream>>>(ws, mf, Wv, bv, out);
  else
    attn_kernel<false><<<1024, 256, 0, stream>>>(ws, mf, Wv, bv, out);
}

// Round 11
// 336.461 us; speedup vs baseline: 1.3477x; 1.3477x over previous
//
#include <hip/hip_runtime.h>

// Problem constants (B=2, S=4096, D=512, H=8, Dh=64). f32 I/O, bf16 MFMA inside.
#define MTOT 8192  // B*S

typedef __attribute__((ext_vector_type(8))) short bf16x8;
typedef __attribute__((ext_vector_type(4))) float f32x4;

#if __has_builtin(__builtin_amdgcn_exp2f)
#define EXP2F __builtin_amdgcn_exp2f
#else
#define EXP2F exp2f
#endif

#define SC 0.18033688011112042f  // (1/8) * log2(e), folded into K
#define LDP 72                   // bf16 LDS row stride: 36 dw == 4 mod 32
#define CTS 136                  // gemm epilogue C-tile stride (el)
#define MOS 68                   // f32 merge-buffer stride: 68 == 4 mod 32

static __device__ __forceinline__ unsigned short tb(float f) {
  union { float f; unsigned int i; } x;
  x.f = f;
  return (unsigned short)(x.i >> 16);
}
static __device__ __forceinline__ unsigned int pkt(float a, float b) {
  union { float f; unsigned int i; } xa, xb;
  xa.f = a; xb.f = b;
  return (xa.i >> 16) | (xb.i & 0xFFFF0000u);
}
static __device__ __forceinline__ bf16x8 ld8f32_bf16(const float* __restrict__ p) {
  f32x4 lo = *(const f32x4*)p;
  f32x4 hi = *(const f32x4*)(p + 4);
  union { unsigned int u[4]; bf16x8 v; } r;
  r.u[0] = pkt(lo[0], lo[1]);
  r.u[1] = pkt(lo[2], lo[3]);
  r.u[2] = pkt(hi[0], hi[1]);
  r.u[3] = pkt(hi[2], hi[3]);
  return r.v;
}
static __device__ __forceinline__ bf16x8 comb64(uint2 lo, uint2 hi) {
  union { uint2 p[2]; bf16x8 v; } r;
  r.p[0] = lo; r.p[1] = hi;
  return r.v;
}

// ---------------------------------------------------------------------------
// Kernel 1: projection GEMM (unchanged from R10 for attribution).
// Columns: [0,512) Q -> Q_ws[bh][s][dh]; [512,1024) V -> Vt_ws[bh][dh][s];
//          [1024,1536) K (*SC) -> K_ws[bh][s][dh] (only when nct==12).
// ---------------------------------------------------------------------------
__global__ __launch_bounds__(256) void gemm_qvk(
    const float* __restrict__ mf,
    const float* __restrict__ Wc,
    const float* __restrict__ bc,
    const float* __restrict__ Wv,
    const float* __restrict__ bv,
    unsigned short* __restrict__ ws,
    int nct)
{
  const int bid = blockIdx.x;
  const int tn = bid % nct, tm = bid / nct;
  const int w = threadIdx.x >> 6, lane = threadIdx.x & 63;
  const int n = lane & 15, q = lane >> 4;

  __shared__ alignas(16) unsigned short smem[2 * 128 * LDP];  // As | Bs; Ct overlay
  unsigned short* As = smem;
  unsigned short* Bs = smem + 128 * LDP;

  f32x4 acc[4][4] = {};
  const int rowA0 = tm * 128, colB0 = tn * 128;
  const int sr = threadIdx.x >> 4;
  const int sc4 = (threadIdx.x & 15) * 4;

  for (int kc = 0; kc < 512; kc += 64) {
    __syncthreads();
#pragma unroll
    for (int rr = 0; rr < 8; ++rr) {
      const int row = rr * 16 + sr;
      f32x4 av = *(const f32x4*)(mf + (size_t)(rowA0 + row) * 512 + kc + sc4);
      uint2 ap; ap.x = pkt(av[0], av[1]); ap.y = pkt(av[2], av[3]);
      *(uint2*)(&As[row * LDP + sc4]) = ap;
      const int cB = colB0 + row;
      const float* bsrc = (cB < 1024) ? (Wc + (size_t)cB * 512)
                                      : (Wv + (size_t)(cB - 1024) * 512);
      f32x4 bvx = *(const f32x4*)(bsrc + kc + sc4);
      uint2 bp; bp.x = pkt(bvx[0], bvx[1]); bp.y = pkt(bvx[2], bvx[3]);
      *(uint2*)(&Bs[row * LDP + sc4]) = bp;
    }
    __syncthreads();
#pragma unroll
    for (int ks = 0; ks < 2; ++ks) {
      bf16x8 a[4], b[4];
#pragma unroll
      for (int si = 0; si < 4; ++si)
        a[si] = *(const bf16x8*)(&As[((w >> 1) * 64 + si * 16 + n) * LDP + ks * 32 + q * 8]);
#pragma unroll
      for (int sj = 0; sj < 4; ++sj)
        b[sj] = *(const bf16x8*)(&Bs[((w & 1) * 64 + sj * 16 + n) * LDP + ks * 32 + q * 8]);
#pragma unroll
      for (int si = 0; si < 4; ++si)
#pragma unroll
        for (int sj = 0; sj < 4; ++sj)
          acc[si][sj] = __builtin_amdgcn_mfma_f32_16x16x32_bf16(a[si], b[sj], acc[si][sj], 0, 0, 0);
    }
  }

  __syncthreads();
  unsigned short* Ct = smem;
  const bool isV = (tn >= 4 && tn < 8);
  const int rl0 = (w >> 1) * 64, cl0 = (w & 1) * 64;

  if (!isV) {
    const bool isK = (tn >= 8);
#pragma unroll
    for (int sj = 0; sj < 4; ++sj) {
      const int c = colB0 + sj * 16 + n;
      const float bias = isK ? bv[c - 1024] : bc[c];
#pragma unroll
      for (int si = 0; si < 4; ++si)
#pragma unroll
        for (int r = 0; r < 4; ++r) {
          float v = acc[si][sj][r] + bias;
          if (isK) v *= SC;
          Ct[(rl0 + si * 16 + q * 4 + r) * CTS + cl0 + sj * 16 + n] = tb(v);
        }
    }
  } else {
#pragma unroll
    for (int sj = 0; sj < 4; ++sj) {
      const float bias = bc[colB0 + sj * 16 + n];
#pragma unroll
      for (int si = 0; si < 4; ++si) {
        uint2 pk;
        pk.x = pkt(acc[si][sj][0] + bias, acc[si][sj][1] + bias);
        pk.y = pkt(acc[si][sj][2] + bias, acc[si][sj][3] + bias);
        *(uint2*)(&Ct[(cl0 + sj * 16 + n) * CTS + rl0 + si * 16 + q * 4]) = pk;
      }
    }
  }
  __syncthreads();

  const int rk = threadIdx.x & 7, rr2 = threadIdx.x >> 3;
#pragma unroll
  for (int rp = 0; rp < 4; ++rp) {
    const int row = rp * 32 + rr2;
#pragma unroll
    for (int ch = 0; ch < 2; ++ch) {
      const int col = ch * 64 + rk * 8;
      bf16x8 v = *(const bf16x8*)(&Ct[row * CTS + col]);
      if (!isV) {
        const int srow = rowA0 + row;
        const int bb = srow >> 12, ss = srow & 4095;
        const int cg = colB0 + col;
        const int cl = (cg >= 1024) ? (cg - 1024) : cg;
        const int hh = cl >> 6, dh0 = cl & 63;
        unsigned short* base = (cg >= 1024) ? (ws + (size_t)2 * MTOT * 512) : ws;
        *(bf16x8*)(base + ((size_t)((bb * 8 + hh) * 4096 + ss)) * 64 + dh0) = v;
      } else {
        const int cv = (tn - 4) * 128 + row;
        const int hh = cv >> 6, dh0 = cv & 63;
        const int sg = rowA0 + col;
        const int bb = sg >> 12, ss = sg & 4095;
        *(bf16x8*)(ws + (size_t)MTOT * 512 +
                   ((size_t)((bb * 8 + hh) * 64 + dh0)) * 4096 + ss) = v;
      }
    }
  }
}

// ---------------------------------------------------------------------------
// Kernel 2: flash attention = R9 dataflow + phase-wise body + VALU-l.
//  - block = 2 waves x 64 i-rows shared; waves split j (exact f32 merge)
//  - phases: [ALL 32 QK MFMAs] -> [reload bq] -> [ALL exp2/pack/l] ->
//            [ALL 32 PV MFMAs] -> [reload bvv]; register-P throughout
//  - l via VALU row-sum + 2 shfl_xor (saves 8 MFMAs/iter on the hot pipe)
//  - NO launch-bounds min (R10's (256,3) cap caused spills: VGPR 128->84)
// ---------------------------------------------------------------------------
template <bool KWS>
__global__ __launch_bounds__(128) void attn_kernel(
    const unsigned short* __restrict__ qvws,
    const float* __restrict__ mf,
    const float* __restrict__ Wv,
    const float* __restrict__ bv,
    float* __restrict__ out)
{
  const int bid = blockIdx.x;
  const int bh = ((bid & 7) << 1) | ((bid >> 3) & 1);  // XCD-local bh pairing
  const int ib = bid >> 4;
  const int b_ = bh >> 3, h = bh & 7;
  const int w = threadIdx.x >> 6, lane = threadIdx.x & 63;
  const int n = lane & 15, q = lane >> 4;
  const int i0 = ib * 64;

  __shared__ alignas(16) float mO[64 * MOS];  // merge/out staging
  __shared__ float lbuf[2][64];

  const unsigned short* Qb = qvws + (size_t)(bh * 4096) * 64;
  const unsigned short* Vb = qvws + (size_t)MTOT * 512 + (size_t)(bh * 64) * 4096;

  bf16x8 aK[4][2];
  if (KWS) {
    const unsigned short* Kb = qvws + (size_t)2 * MTOT * 512 + (size_t)(bh * 4096) * 64;
#pragma unroll
    for (int sub = 0; sub < 4; ++sub)
#pragma unroll
      for (int s = 0; s < 2; ++s)
        aK[sub][s] = *(const bf16x8*)(Kb + (size_t)(i0 + sub * 16 + n) * 64 + s * 32 + q * 8);
  } else {
    // Fallback: compute 64-row K tile; wave w does subs {2w, 2w+1}; via mO-as-LDS.
    unsigned short* Ks = (unsigned short*)mO;
    f32x4 ka[2][4] = {};
    for (int kk = 0; kk < 512; kk += 32) {
      bf16x8 a0 = ld8f32_bf16(mf + (size_t)(b_ * 4096 + i0 + (2 * w + 0) * 16 + n) * 512 + kk + q * 8);
      bf16x8 a1 = ld8f32_bf16(mf + (size_t)(b_ * 4096 + i0 + (2 * w + 1) * 16 + n) * 512 + kk + q * 8);
#pragma unroll
      for (int t = 0; t < 4; ++t) {
        bf16x8 bw = ld8f32_bf16(Wv + (size_t)(h * 64 + t * 16 + n) * 512 + kk + q * 8);
        ka[0][t] = __builtin_amdgcn_mfma_f32_16x16x32_bf16(a0, bw, ka[0][t], 0, 0, 0);
        ka[1][t] = __builtin_amdgcn_mfma_f32_16x16x32_bf16(a1, bw, ka[1][t], 0, 0, 0);
      }
    }
#pragma unroll
    for (int sl = 0; sl < 2; ++sl)
#pragma unroll
      for (int t = 0; t < 4; ++t) {
        const float bias = bv[h * 64 + t * 16 + n];
#pragma unroll
        for (int r = 0; r < 4; ++r)
          Ks[((2 * w + sl) * 16 + q * 4 + r) * LDP + t * 16 + n] =
              tb((ka[sl][t][r] + bias) * SC);
      }
    __syncthreads();
#pragma unroll
    for (int sub = 0; sub < 4; ++sub)
#pragma unroll
      for (int s = 0; s < 2; ++s)
        aK[sub][s] = *(const bf16x8*)(&Ks[(sub * 16 + n) * LDP + s * 32 + q * 8]);
    __syncthreads();
  }

  f32x4 o[4][4] = {};
  float lacc[4] = {0.f, 0.f, 0.f, 0.f};
  const int jbase = w * 2048;

  // Single-buffered streaming frags (reloaded at phase boundaries).
  bf16x8 bq[4][2], bvv[4][2];
#pragma unroll
  for (int jt = 0; jt < 4; ++jt)
#pragma unroll
    for (int s = 0; s < 2; ++s)
      bq[jt][s] = *(const bf16x8*)(Qb + (size_t)(jbase + jt * 16 + n) * 64 + s * 32 + q * 8);
#pragma unroll
  for (int t = 0; t < 4; ++t)
#pragma unroll
    for (int s = 0; s < 2; ++s) {
      const unsigned short* p0 = Vb + (size_t)(t * 16 + n) * 4096 + jbase + 32 * s + 4 * q;
      bvv[t][s] = comb64(*(const uint2*)p0, *(const uint2*)(p0 + 16));
    }

  for (int it = 0; it < 32; ++it) {
    const int jn = jbase + ((it + 1) & 31) * 64;

    // ---- Phase 1: ALL QK (32 MFMAs, 16 independent depth-2 chains) ----
    f32x4 c[4][4] = {};
#pragma unroll
    for (int sub = 0; sub < 4; ++sub)
#pragma unroll
      for (int jt = 0; jt < 4; ++jt)
#pragma unroll
        for (int s = 0; s < 2; ++s)
          c[sub][jt] = __builtin_amdgcn_mfma_f32_16x16x32_bf16(bq[jt][s], aK[sub][s], c[sub][jt], 0, 0, 0);

    // ---- Phase 2: bq dead -> issue next-iter Q loads ----
#pragma unroll
    for (int jt = 0; jt < 4; ++jt)
#pragma unroll
      for (int s = 0; s < 2; ++s)
        bq[jt][s] = *(const bf16x8*)(Qb + (size_t)(jn + jt * 16 + n) * 64 + s * 32 + q * 8);

    // ---- Phase 3: ALL exp2 + pack + VALU row-sum for l ----
    bf16x8 pa[4][2];
#pragma unroll
    for (int sub = 0; sub < 4; ++sub) {
      float sum = 0.f;
#pragma unroll
      for (int s = 0; s < 2; ++s) {
        float e0 = EXP2F(c[sub][2 * s][0]), e1 = EXP2F(c[sub][2 * s][1]);
        float e2 = EXP2F(c[sub][2 * s][2]), e3 = EXP2F(c[sub][2 * s][3]);
        float e4 = EXP2F(c[sub][2 * s + 1][0]), e5 = EXP2F(c[sub][2 * s + 1][1]);
        float e6 = EXP2F(c[sub][2 * s + 1][2]), e7 = EXP2F(c[sub][2 * s + 1][3]);
        sum += ((e0 + e1) + (e2 + e3)) + ((e4 + e5) + (e6 + e7));
        union { unsigned int u[4]; bf16x8 v; } p;
        p.u[0] = pkt(e0, e1);
        p.u[1] = pkt(e2, e3);
        p.u[2] = pkt(e4, e5);
        p.u[3] = pkt(e6, e7);
        pa[sub][s] = p.v;
      }
      // Reduce over the 4 q-groups: lanes {n, n+16, n+32, n+48} -> l for i=sub*16+n.
      sum += __shfl_xor(sum, 16);
      sum += __shfl_xor(sum, 32);
      lacc[sub] += sum;
    }

    // ---- Phase 4: ALL PV (32 MFMAs) ----
#pragma unroll
    for (int sub = 0; sub < 4; ++sub)
#pragma unroll
      for (int s = 0; s < 2; ++s)
#pragma unroll
        for (int t = 0; t < 4; ++t)
          o[sub][t] = __builtin_amdgcn_mfma_f32_16x16x32_bf16(pa[sub][s], bvv[t][s], o[sub][t], 0, 0, 0);

    // ---- Phase 5: bvv dead -> issue next-iter V loads ----
#pragma unroll
    for (int t = 0; t < 4; ++t)
#pragma unroll
      for (int s = 0; s < 2; ++s) {
        const unsigned short* p0 = Vb + (size_t)(t * 16 + n) * 4096 + jn + 32 * s + 4 * q;
        bvv[t][s] = comb64(*(const uint2*)p0, *(const uint2*)(p0 + 16));
      }
  }

  // ---- merge j-halves (exact f32) + epilogue ----
  __syncthreads();
  if (q == 0)
#pragma unroll
    for (int sub = 0; sub < 4; ++sub)
      lbuf[w][sub * 16 + n] = lacc[sub];
  const int eb = w ? 0 : 32, es0 = w ? 0 : 2;   // rows/subs I export
#pragma unroll
  for (int sl = 0; sl < 2; ++sl) {
    const int sub = es0 + sl;
#pragma unroll
    for (int t = 0; t < 4; ++t)
#pragma unroll
      for (int r = 0; r < 4; ++r)
        mO[(eb + sl * 16 + q * 4 + r) * MOS + t * 16 + n] = o[sub][t][r];
  }
  __syncthreads();
  const int ks0 = w ? 2 : 0;                    // subs I keep (rows sub*16..)
#pragma unroll
  for (int sl = 0; sl < 2; ++sl) {
    const int sub = ks0 + sl;
    float li[4];
#pragma unroll
    for (int r = 0; r < 4; ++r) {
      const int il = sub * 16 + q * 4 + r;
      li[r] = 1.0f / (lbuf[0][il] + lbuf[1][il]);
    }
#pragma unroll
    for (int t = 0; t < 4; ++t)
#pragma unroll
      for (int r = 0; r < 4; ++r) {
        const int mrow = sub * 16 + q * 4 + r;
        const int mcol = t * 16 + n;
        mO[mrow * MOS + mcol] = (o[sub][t][r] + mO[mrow * MOS + mcol]) * li[r];
      }
  }
  __syncthreads();
  // Coalesced f32x4 out stores: 2 threads per row, 128B each.
  const int orow = threadIdx.x >> 1, ohalf = (threadIdx.x & 1) * 32;
  const size_t obase = (size_t)(b_ * 4096 + i0 + orow) * 512 + h * 64 + ohalf;
#pragma unroll
  for (int c4 = 0; c4 < 8; ++c4) {
    f32x4 v = *(const f32x4*)(&mO[orow * MOS + ohalf + c4 * 4]);
    f32x4 m = *(const f32x4*)(mf + obase + c4 * 4);
    *(f32x4*)(out + obase + c4 * 4) = v + m;
  }
}

extern "C" void kernel_launch(void* const* d_in, const int* in_sizes, int n_in,
                              void* d_out, int out_size, void* d_ws, size_t ws_size,
                              hipStream_t stream) {
  const float* mf = (const float*)d_in[0];  // (2,4096,512) f32
  const float* Wc = (const float*)d_in[1];  // (1024,512) f32
  const float* bc = (const float*)d_in[2];  // (1024,) f32
  const float* Wv = (const float*)d_in[3];  // (512,512) f32
  const float* bv = (const float*)d_in[4];  // (512,) f32
  float* out = (float*)d_out;
  unsigned short* ws = (unsigned short*)d_ws;

  const bool kws = ws_size >= (size_t)3 * MTOT * 512 * 2;  // Q+V^T+K bf16 = 24 MiB
  const int nct = kws ? 12 : 8;

  gemm_qvk<<<64 * nct, 256, 0, stream>>>(mf, Wc, bc, Wv, bv, ws, nct);
  if (kws)
    attn_kernel<true><<<1024, 128, 0, stream>>>(ws, mf, Wv, bv, out);
  else
    attn_kernel<false><<<1024, 128, 0, stream>>>(ws, mf, Wv, bv, out);
}